// Round 1
// baseline (1275.528 us; speedup 1.0000x reference)
//
#include <hip/hip_runtime.h>

#define BATCH 1024
#define TT    512
#define HH    64
#define G4    256   // 4*H gate rows
#define NB    4     // batches per block

__device__ __forceinline__ float sigmoidf_(float x) {
    return 1.0f / (1.0f + __expf(-x));
}
__device__ __forceinline__ float tanhf_(float x) {
    // 1 - 2/(1+e^{2x}); exact at +-inf via fp32 inf semantics
    return 1.0f - 2.0f / (1.0f + __expf(2.0f * x));
}

// grid 256 blocks x 768 threads. Block owns NB=4 batches for the whole T loop.
// Group A (tid 0..255):   layer1 gate row g (w_hh0 row in regs) + layer1 pointwise
// Group B (tid 256..511): layer2 w_ih1 row in regs (needs h1_new) + layer2 pointwise
// Group C (tid 512..767): layer2 w_hh1 row in regs (h2_prev partial, overlaps A)
__global__ __launch_bounds__(768) void lstm_fused(
    const float* __restrict__ x,
    const float* __restrict__ w_ih0, const float* __restrict__ w_hh0,
    const float* __restrict__ b_ih0, const float* __restrict__ b_hh0,
    const float* __restrict__ w_ih1, const float* __restrict__ w_hh1,
    const float* __restrict__ b_ih1, const float* __restrict__ b_hh1,
    const float* __restrict__ w_out, const float* __restrict__ b_out,
    float* __restrict__ out)
{
    __shared__ float4 h1s[HH];      // h1[j] for 4 batches
    __shared__ float4 h2s[HH];      // h2[j] for 4 batches
    __shared__ float4 g1s[G4];      // layer1 gates
    __shared__ float4 g2p[G4];      // layer2 recurrent partial (incl. bias)
    __shared__ float4 g2s[G4];      // layer2 gates
    __shared__ float  xs[2][3][NB]; // double-buffered x_t
    __shared__ float  lg[NB][4];    // logits

    const int tid   = threadIdx.x;
    const int group = tid >> 8;     // 0=A,1=B,2=C (wave-uniform: 256 = 4 waves)
    const int g     = tid & 255;
    const int b0    = blockIdx.x * NB;

    // --- persistent weight row in registers (64 VGPRs) ---
    float wreg[HH];
    const float* wsrc = (group == 0) ? (w_hh0 + g * HH)
                      : (group == 1) ? (w_ih1 + g * HH)
                                     : (w_hh1 + g * HH);
    #pragma unroll
    for (int j = 0; j < HH; ++j) wreg[j] = wsrc[j];

    float wx0 = 0.f, wx1 = 0.f, wx2 = 0.f, bias = 0.f;
    if (group == 0) {
        wx0 = w_ih0[g * 3 + 0];
        wx1 = w_ih0[g * 3 + 1];
        wx2 = w_ih0[g * 3 + 2];
        bias = b_ih0[g] + b_hh0[g];
    } else if (group == 2) {
        bias = b_ih1[g] + b_hh1[g];
    }

    float c_reg = 0.0f;  // A threads: c1[j][b]; B threads: c2[j][b]

    if (tid < HH) {
        h1s[tid] = make_float4(0.f, 0.f, 0.f, 0.f);
        h2s[tid] = make_float4(0.f, 0.f, 0.f, 0.f);
    }
    if (tid < 12) {
        const int b = tid & 3, d = tid >> 2;
        xs[0][d][b] = x[((size_t)(b0 + b) * TT + 0) * 3 + d];
    }
    __syncthreads();

    for (int t = 0; t < TT; ++t) {
        const int buf = t & 1;

        // ---- Phase 1: A: layer1 gates;  C: layer2 recurrent partial;  B: stage x_{t+1}
        if (group == 0) {
            float a0 = bias, a1 = bias, a2 = bias, a3 = bias;
            a0 += wx0 * xs[buf][0][0] + wx1 * xs[buf][1][0] + wx2 * xs[buf][2][0];
            a1 += wx0 * xs[buf][0][1] + wx1 * xs[buf][1][1] + wx2 * xs[buf][2][1];
            a2 += wx0 * xs[buf][0][2] + wx1 * xs[buf][1][2] + wx2 * xs[buf][2][2];
            a3 += wx0 * xs[buf][0][3] + wx1 * xs[buf][1][3] + wx2 * xs[buf][2][3];
            #pragma unroll
            for (int j = 0; j < HH; ++j) {
                const float4 hv = h1s[j];   // wave-wide broadcast read
                a0 = fmaf(wreg[j], hv.x, a0);
                a1 = fmaf(wreg[j], hv.y, a1);
                a2 = fmaf(wreg[j], hv.z, a2);
                a3 = fmaf(wreg[j], hv.w, a3);
            }
            g1s[g] = make_float4(a0, a1, a2, a3);
        } else if (group == 2) {
            float a0 = bias, a1 = bias, a2 = bias, a3 = bias;
            #pragma unroll
            for (int j = 0; j < HH; ++j) {
                const float4 hv = h2s[j];
                a0 = fmaf(wreg[j], hv.x, a0);
                a1 = fmaf(wreg[j], hv.y, a1);
                a2 = fmaf(wreg[j], hv.z, a2);
                a3 = fmaf(wreg[j], hv.w, a3);
            }
            g2p[g] = make_float4(a0, a1, a2, a3);
        } else {
            if (g < 12 && (t + 1) < TT) {
                const int b = g & 3, d = g >> 2;
                xs[1 - buf][d][b] = x[((size_t)(b0 + b) * TT + (t + 1)) * 3 + d];
            }
        }
        __syncthreads();

        // ---- Phase 2: layer1 pointwise (group A; thread -> (j = g>>2, b = g&3))
        if (group == 0) {
            const int b = g & 3, j = g >> 2;
            const float* gf = (const float*)g1s;
            const float iv = gf[(j      ) * 4 + b];
            const float fv = gf[(j +  64) * 4 + b];
            const float gv = gf[(j + 128) * 4 + b];
            const float ov = gf[(j + 192) * 4 + b];
            const float is = sigmoidf_(iv);
            const float fs = sigmoidf_(fv);
            const float gt = tanhf_(gv);
            const float os = sigmoidf_(ov);
            c_reg = fs * c_reg + is * gt;
            ((float*)h1s)[j * 4 + b] = os * tanhf_(c_reg);
        }
        __syncthreads();

        // ---- Phase 3: B: layer2 gates = partial + w_ih1 . h1_new
        if (group == 1) {
            const float4 p = g2p[g];
            float a0 = p.x, a1 = p.y, a2 = p.z, a3 = p.w;
            #pragma unroll
            for (int j = 0; j < HH; ++j) {
                const float4 hv = h1s[j];
                a0 = fmaf(wreg[j], hv.x, a0);
                a1 = fmaf(wreg[j], hv.y, a1);
                a2 = fmaf(wreg[j], hv.z, a2);
                a3 = fmaf(wreg[j], hv.w, a3);
            }
            g2s[g] = make_float4(a0, a1, a2, a3);
        }
        __syncthreads();

        // ---- Phase 4: layer2 pointwise (group B)
        if (group == 1) {
            const int b = g & 3, j = g >> 2;
            const float* gf = (const float*)g2s;
            const float iv = gf[(j      ) * 4 + b];
            const float fv = gf[(j +  64) * 4 + b];
            const float gv = gf[(j + 128) * 4 + b];
            const float ov = gf[(j + 192) * 4 + b];
            const float is = sigmoidf_(iv);
            const float fs = sigmoidf_(fv);
            const float gt = tanhf_(gv);
            const float os = sigmoidf_(ov);
            c_reg = fs * c_reg + is * gt;
            ((float*)h2s)[j * 4 + b] = os * tanhf_(c_reg);
        }
        __syncthreads();
    }

    // ---- Epilogue: logits + softmax for the block's 4 batches
    if (tid < 16) {
        const int b = tid & 3, o = tid >> 2;
        float acc = b_out[o];
        const float* h2f = (const float*)h2s;
        #pragma unroll
        for (int j = 0; j < HH; ++j)
            acc = fmaf(w_out[o * HH + j], h2f[j * 4 + b], acc);
        lg[b][o] = acc;
    }
    __syncthreads();
    if (tid < NB) {
        const int b = tid;
        const float l0 = lg[b][0], l1 = lg[b][1], l2 = lg[b][2], l3 = lg[b][3];
        const float m  = fmaxf(fmaxf(l0, l1), fmaxf(l2, l3));
        const float e0 = __expf(l0 - m), e1 = __expf(l1 - m);
        const float e2 = __expf(l2 - m), e3 = __expf(l3 - m);
        const float s  = 1.0f / (e0 + e1 + e2 + e3);
        out[(b0 + b) * 4 + 0] = e0 * s;
        out[(b0 + b) * 4 + 1] = e1 * s;
        out[(b0 + b) * 4 + 2] = e2 * s;
        out[(b0 + b) * 4 + 3] = e3 * s;
    }
}

extern "C" void kernel_launch(void* const* d_in, const int* in_sizes, int n_in,
                              void* d_out, int out_size, void* d_ws, size_t ws_size,
                              hipStream_t stream) {
    const float* x     = (const float*)d_in[0];
    const float* w_ih0 = (const float*)d_in[1];
    const float* w_hh0 = (const float*)d_in[2];
    const float* b_ih0 = (const float*)d_in[3];
    const float* b_hh0 = (const float*)d_in[4];
    const float* w_ih1 = (const float*)d_in[5];
    const float* w_hh1 = (const float*)d_in[6];
    const float* b_ih1 = (const float*)d_in[7];
    const float* b_hh1 = (const float*)d_in[8];
    const float* w_out = (const float*)d_in[9];
    const float* b_out = (const float*)d_in[10];
    float* out = (float*)d_out;

    hipLaunchKernelGGL(lstm_fused, dim3(BATCH / NB), dim3(768), 0, stream,
                       x, w_ih0, w_hh0, b_ih0, b_hh0,
                       w_ih1, w_hh1, b_ih1, b_hh1,
                       w_out, b_out, out);
}